// Round 5
// baseline (245.057 us; speedup 1.0000x reference)
//
#include <hip/hip_runtime.h>

#define NB 8
#define CC 3
#define HH 720
#define WW 1280
#define EPSL 1e-6f
#define HSEG 40            // 720 = 18*40; NITER = 48 = 6*8 (unroll-friendly)
#define NSEG (HH / HSEG)   // 18
#define OUTC 56            // output cols per wave (64 lanes - 8 halo)
#define NSTRIP 23          // 23*56 = 1288 >= 1280
#define NWAVES (NSTRIP * NSEG * NB)  // 3312
#define NBLK (NWAVES / 4)            // 828 blocks

// One pipelined row-iteration. J in [0,8) (static under unroll); ITER = row
// counter (runtime ok, only feeds addresses). DO_OUT: emit output row ITER-8.
#define ITER_BODY(J, ITER, DO_OUT)                                         \
  {                                                                        \
    const int r = r0 + (ITER);                                             \
    /* (1) loads for row r+2 (consumed next iter) */                       \
    int rcl2 = min(max(r + 2, 0), HH - 1);                                 \
    size_t ro2 = (size_t)rcl2 * WW + gcc;                                  \
    float dC  = dispn[ro2];                                                \
    float cl0 = leftn[ro2];                                                \
    float cl1 = leftn[plane + ro2];                                        \
    float cl2 = leftn[2 * plane + ro2];                                    \
    /* (2) gathers for row r+1 using dB (loaded last iter) */              \
    float bw0, bw1, bg00, bg01, bg10, bg11, bg20, bg21;                    \
    {                                                                      \
      float ix  = (float)gc - dB;                                          \
      float x0f = floorf(ix), wx = ix - x0f;                               \
      int x0i = (int)x0f, x1i = x0i + 1;                                   \
      float v0 = (x0i >= 0 && x0i < WW) ? 1.f : 0.f;                       \
      float v1 = (x1i >= 0 && x1i < WW) ? 1.f : 0.f;                       \
      int i0 = min(max(x0i, 0), WW - 1), i1 = min(max(x1i, 0), WW - 1);    \
      bw0 = v0 * (1.f - wx); bw1 = v1 * wx;                                \
      size_t rb = (size_t)min(max(r + 1, 0), HH - 1) * WW;                 \
      bg00 = rightn[rb + i0];               bg01 = rightn[rb + i1];        \
      bg10 = rightn[plane + rb + i0];       bg11 = rightn[plane + rb + i1];\
      bg20 = rightn[2 * plane + rb + i0];   bg21 = rightn[2 * plane + rb + i1];\
    }                                                                      \
    /* (3) combine raw channel sums for row r */                           \
    float rca = ag00 * aw0 + ag01 * aw1;                                   \
    float rcb = ag10 * aw0 + ag11 * aw1;                                   \
    float rcc = ag20 * aw0 + ag21 * aw1;                                   \
    bool valr = (r >= 0) && (r < HH) && (gc >= 0) && (gc < WW);            \
    float rx = al0 + al1 + al2;                                            \
    float ry = al0 * al0 + al1 * al1 + al2 * al2;                          \
    float rz = rca + rcb + rcc;                                            \
    float rw = rca * rca + rcb * rcb + rcc * rcc;                          \
    rx = valr ? rx : 0.f;  ry = valr ? ry : 0.f;                           \
    rz = valr ? rz : 0.f;  rw = valr ? rw : 0.f;                           \
    /* (4) tree h-box: sum x[lane-4..lane+4], 5 shuffles/comp */           \
    float hx, hy, hz, hw, s;                                               \
    s = rx + __shfl(rx, lane + 1, 64);                                     \
    s = s + __shfl(s, lane + 2, 64);                                       \
    s = s + __shfl(s, lane + 4, 64);                                       \
    hx = __shfl(s, lane - 4, 64) + __shfl(rx, lane + 4, 64);               \
    s = ry + __shfl(ry, lane + 1, 64);                                     \
    s = s + __shfl(s, lane + 2, 64);                                       \
    s = s + __shfl(s, lane + 4, 64);                                       \
    hy = __shfl(s, lane - 4, 64) + __shfl(ry, lane + 4, 64);               \
    s = rz + __shfl(rz, lane + 1, 64);                                     \
    s = s + __shfl(s, lane + 2, 64);                                       \
    s = s + __shfl(s, lane + 4, 64);                                       \
    hz = __shfl(s, lane - 4, 64) + __shfl(rz, lane + 4, 64);               \
    s = rw + __shfl(rw, lane + 1, 64);                                     \
    s = s + __shfl(s, lane + 2, 64);                                       \
    s = s + __shfl(s, lane + 4, 64);                                       \
    hw = __shfl(s, lane - 4, 64) + __shfl(rw, lane + 4, 64);               \
    /* (5) vertical rolling add */                                         \
    vsum.x += hx; vsum.y += hy; vsum.z += hz; vsum.w += hw;                \
    if (DO_OUT) {                                                          \
      float ml   = vsum.x * (1.f / 81.f);                                  \
      float msl  = vsum.y * (1.f / 81.f);                                  \
      float stdl = (msl - ml * ml) * (81.f / 80.f);                        \
      float denl = stdl + EPSL;                                            \
      float invl = __builtin_amdgcn_rcpf(denl);                            \
      invl = fmaf(fmaf(-denl, invl, 1.f), invl, invl);                     \
      float mr   = vsum.z * (1.f / 81.f);                                  \
      float msr  = vsum.w * (1.f / 81.f);                                  \
      float stdr = (msr - mr * mr) * (81.f / 80.f);                        \
      float denr = stdr + EPSL;                                            \
      float invr = __builtin_amdgcn_rcpf(denr);                            \
      invr = fmaf(fmaf(-denr, invr, 1.f), invr, invr);                     \
      if (out_lane) {                                                      \
        float av, bv;                                                      \
        av = (pxl0[(J) & 3] - ml) * invl;                                  \
        bv = (pxr0[(J) & 3] - mr) * invr;                                  \
        acc += fabsf((av - bv) * stdl);                                    \
        av = (pxl1[(J) & 3] - ml) * invl;                                  \
        bv = (pxr1[(J) & 3] - mr) * invr;                                  \
        acc += fabsf((av - bv) * stdl);                                    \
        av = (pxl2[(J) & 3] - ml) * invl;                                  \
        bv = (pxr2[(J) & 3] - mr) * invr;                                  \
        acc += fabsf((av - bv) * stdl);                                    \
      }                                                                    \
      float4 oldr = ring[(J) & 7];  /* h-boxed row from ITER-8 */          \
      vsum.x -= oldr.x; vsum.y -= oldr.y;                                  \
      vsum.z -= oldr.z; vsum.w -= oldr.w;                                  \
    }                                                                      \
    ring[(J) & 7] = make_float4(hx, hy, hz, hw);                           \
    pxl0[(J) & 3] = al0; pxl1[(J) & 3] = al1; pxl2[(J) & 3] = al2;         \
    pxr0[(J) & 3] = rca; pxr1[(J) & 3] = rcb; pxr2[(J) & 3] = rcc;         \
    /* rotate packets: B -> A, C -> B (renamed, not moved, under unroll) */\
    al0 = bl0; al1 = bl1; al2 = bl2;                                       \
    aw0 = bw0; aw1 = bw1;                                                  \
    ag00 = bg00; ag01 = bg01; ag10 = bg10; ag11 = bg11;                    \
    ag20 = bg20; ag21 = bg21;                                              \
    dB = dC; bl0 = cl0; bl1 = cl1; bl2 = cl2;                              \
  }

__global__ __launch_bounds__(256)
void fused_loss_kernel(const float* __restrict__ left,
                       const float* __restrict__ right,
                       const float* __restrict__ disp,
                       float* __restrict__ out)
{
    const int t    = threadIdx.x;
    const int lane = t & 63;
    const int u    = blockIdx.x * 4 + (t >> 6);
    const int strip = u % NSTRIP;
    const int hseg  = (u / NSTRIP) % NSEG;
    const int n     = u / (NSTRIP * NSEG);
    const int h0 = hseg * HSEG;
    const int gc  = strip * OUTC + lane - 4;
    const int gcc = min(max(gc, 0), WW - 1);
    const bool out_lane = (lane >= 4) && (lane < 4 + OUTC) && (gc < WW);
    const size_t plane = (size_t)HH * WW;
    const float* __restrict__ dispn  = disp  + (size_t)n * plane;
    const float* __restrict__ leftn  = left  + (size_t)n * CC * plane;
    const float* __restrict__ rightn = right + (size_t)n * CC * plane;
    const int r0 = h0 - 4;

    float4 ring[8];                       // h-boxed row history (depth 8)
    float pxl0[4], pxl1[4], pxl2[4];      // center-row pixel history (delay 4)
    float pxr0[4], pxr1[4], pxr2[4];

    // ---- prologue: load packets for rows r0 (A) and r0+1 (B) ----
    int rcl = min(max(r0, 0), HH - 1);
    size_t ro = (size_t)rcl * WW + gcc;
    float dA  = dispn[ro];
    float al0 = leftn[ro], al1 = leftn[plane + ro], al2 = leftn[2 * plane + ro];
    rcl = min(max(r0 + 1, 0), HH - 1);
    ro  = (size_t)rcl * WW + gcc;
    float dB  = dispn[ro];
    float bl0 = leftn[ro], bl1 = leftn[plane + ro], bl2 = leftn[2 * plane + ro];

    float aw0, aw1, ag00, ag01, ag10, ag11, ag20, ag21;
    {
        float ix  = (float)gc - dA;
        float x0f = floorf(ix), wx = ix - x0f;
        int x0i = (int)x0f, x1i = x0i + 1;
        float v0 = (x0i >= 0 && x0i < WW) ? 1.f : 0.f;
        float v1 = (x1i >= 0 && x1i < WW) ? 1.f : 0.f;
        int i0 = min(max(x0i, 0), WW - 1), i1 = min(max(x1i, 0), WW - 1);
        aw0 = v0 * (1.f - wx); aw1 = v1 * wx;
        size_t rb = (size_t)min(max(r0, 0), HH - 1) * WW;
        ag00 = rightn[rb + i0];             ag01 = rightn[rb + i1];
        ag10 = rightn[plane + rb + i0];     ag11 = rightn[plane + rb + i1];
        ag20 = rightn[2 * plane + rb + i0]; ag21 = rightn[2 * plane + rb + i1];
    }

    float4 vsum = make_float4(0.f, 0.f, 0.f, 0.f);
    float acc = 0.f;

    // ---- staging: iters 0..7 (fills ring + pixel history; no output) ----
#pragma unroll
    for (int j = 0; j < 8; ++j) ITER_BODY(j, j, false)

    // ---- steady state: iters 8..47, one output row each ----
    for (int big = 1; big < 6; ++big) {
        const int base = big * 8;
#pragma unroll
        for (int j = 0; j < 8; ++j) ITER_BODY(j, base + j, true)
    }

    // ---- reduction: wave shuffle -> LDS (4 slots) -> atomic ----
#pragma unroll
    for (int off = 32; off > 0; off >>= 1)
        acc += __shfl_down(acc, off, 64);
    __shared__ float red[4];
    if (lane == 0) red[t >> 6] = acc;
    __syncthreads();
    if (t == 0) {
        float sred = red[0] + red[1] + red[2] + red[3];
        const float inv_count = 1.f / ((float)NB * CC * HH * WW);
        atomicAdd(out, sred * inv_count);
    }
}

extern "C" void kernel_launch(void* const* d_in, const int* in_sizes, int n_in,
                              void* d_out, int out_size, void* d_ws, size_t ws_size,
                              hipStream_t stream) {
    const float* left  = (const float*)d_in[0];
    const float* right = (const float*)d_in[1];
    const float* disp  = (const float*)d_in[2];
    float* out = (float*)d_out;

    hipMemsetAsync(out, 0, sizeof(float) * out_size, stream);

    hipLaunchKernelGGL(fused_loss_kernel, dim3(NBLK), dim3(256), 0, stream,
                       left, right, disp, out);
}

// Round 6
// 238.458 us; speedup vs baseline: 1.0277x; 1.0277x over previous
//
#include <hip/hip_runtime.h>

#define NB 8
#define CC 3
#define HH 720
#define WW 1280
#define EPSL 1e-6f
#define HSEG 24            // 720 = 30*24; NITER = 32 = 8 staging + 3*8 output
#define NSEG (HH / HSEG)   // 30
#define OUTC 56            // output cols per wave (64 lanes - 8 halo)
#define NSTRIP 23          // 23*56 = 1288 >= 1280
#define NWAVES (NSTRIP * NSEG * NB)  // 5520
#define NBLK (NWAVES / 4)            // 1380 blocks

// One pipelined row-iteration. J in [0,8) (static under unroll); ITER = row
// counter (runtime ok, only feeds addresses). DO_OUT: emit output row ITER-8.
#define ITER_BODY(J, ITER, DO_OUT)                                         \
  {                                                                        \
    const int r = r0 + (ITER);                                             \
    /* (1) loads for row r+2 (consumed next iter) */                       \
    int rcl2 = min(max(r + 2, 0), HH - 1);                                 \
    size_t ro2 = (size_t)rcl2 * WW + gcc;                                  \
    float dC  = dispn[ro2];                                                \
    float cl0 = leftn[ro2];                                                \
    float cl1 = leftn[plane + ro2];                                        \
    float cl2 = leftn[2 * plane + ro2];                                    \
    /* (2) gathers for row r+1 using dB (loaded last iter) */              \
    float bw0, bw1, bg00, bg01, bg10, bg11, bg20, bg21;                    \
    {                                                                      \
      float ix  = (float)gc - dB;                                          \
      float x0f = floorf(ix), wx = ix - x0f;                               \
      int x0i = (int)x0f, x1i = x0i + 1;                                   \
      float v0 = (x0i >= 0 && x0i < WW) ? 1.f : 0.f;                       \
      float v1 = (x1i >= 0 && x1i < WW) ? 1.f : 0.f;                       \
      int i0 = min(max(x0i, 0), WW - 1), i1 = min(max(x1i, 0), WW - 1);    \
      bw0 = v0 * (1.f - wx); bw1 = v1 * wx;                                \
      size_t rb = (size_t)min(max(r + 1, 0), HH - 1) * WW;                 \
      bg00 = rightn[rb + i0];               bg01 = rightn[rb + i1];        \
      bg10 = rightn[plane + rb + i0];       bg11 = rightn[plane + rb + i1];\
      bg20 = rightn[2 * plane + rb + i0];   bg21 = rightn[2 * plane + rb + i1];\
    }                                                                      \
    /* (3) combine raw channel sums for row r */                           \
    float rca = ag00 * aw0 + ag01 * aw1;                                   \
    float rcb = ag10 * aw0 + ag11 * aw1;                                   \
    float rcc = ag20 * aw0 + ag21 * aw1;                                   \
    bool valr = (r >= 0) && (r < HH) && (gc >= 0) && (gc < WW);            \
    float rx = al0 + al1 + al2;                                            \
    float ry = al0 * al0 + al1 * al1 + al2 * al2;                          \
    float rz = rca + rcb + rcc;                                            \
    float rw = rca * rca + rcb * rcb + rcc * rcc;                          \
    rx = valr ? rx : 0.f;  ry = valr ? ry : 0.f;                           \
    rz = valr ? rz : 0.f;  rw = valr ? rw : 0.f;                           \
    /* (4) tree h-box: sum x[lane-4..lane+4], 5 shuffles/comp */           \
    float hx, hy, hz, hw, s;                                               \
    s = rx + __shfl(rx, lane + 1, 64);                                     \
    s = s + __shfl(s, lane + 2, 64);                                       \
    s = s + __shfl(s, lane + 4, 64);                                       \
    hx = __shfl(s, lane - 4, 64) + __shfl(rx, lane + 4, 64);               \
    s = ry + __shfl(ry, lane + 1, 64);                                     \
    s = s + __shfl(s, lane + 2, 64);                                       \
    s = s + __shfl(s, lane + 4, 64);                                       \
    hy = __shfl(s, lane - 4, 64) + __shfl(ry, lane + 4, 64);               \
    s = rz + __shfl(rz, lane + 1, 64);                                     \
    s = s + __shfl(s, lane + 2, 64);                                       \
    s = s + __shfl(s, lane + 4, 64);                                       \
    hz = __shfl(s, lane - 4, 64) + __shfl(rz, lane + 4, 64);               \
    s = rw + __shfl(rw, lane + 1, 64);                                     \
    s = s + __shfl(s, lane + 2, 64);                                       \
    s = s + __shfl(s, lane + 4, 64);                                       \
    hw = __shfl(s, lane - 4, 64) + __shfl(rw, lane + 4, 64);               \
    /* (5) vertical rolling add */                                         \
    vsum.x += hx; vsum.y += hy; vsum.z += hz; vsum.w += hw;                \
    if (DO_OUT) {                                                          \
      float ml   = vsum.x * (1.f / 81.f);                                  \
      float msl  = vsum.y * (1.f / 81.f);                                  \
      float stdl = (msl - ml * ml) * (81.f / 80.f);                        \
      float denl = stdl + EPSL;                                            \
      float invl = __builtin_amdgcn_rcpf(denl);                            \
      invl = fmaf(fmaf(-denl, invl, 1.f), invl, invl);                     \
      float mr   = vsum.z * (1.f / 81.f);                                  \
      float msr  = vsum.w * (1.f / 81.f);                                  \
      float stdr = (msr - mr * mr) * (81.f / 80.f);                        \
      float denr = stdr + EPSL;                                            \
      float invr = __builtin_amdgcn_rcpf(denr);                            \
      invr = fmaf(fmaf(-denr, invr, 1.f), invr, invr);                     \
      if (out_lane) {                                                      \
        float av, bv;                                                      \
        av = (pxl0[(J) & 3] - ml) * invl;                                  \
        bv = (pxr0[(J) & 3] - mr) * invr;                                  \
        acc += fabsf((av - bv) * stdl);                                    \
        av = (pxl1[(J) & 3] - ml) * invl;                                  \
        bv = (pxr1[(J) & 3] - mr) * invr;                                  \
        acc += fabsf((av - bv) * stdl);                                    \
        av = (pxl2[(J) & 3] - ml) * invl;                                  \
        bv = (pxr2[(J) & 3] - mr) * invr;                                  \
        acc += fabsf((av - bv) * stdl);                                    \
      }                                                                    \
      float4 oldr = ring[(J) & 7];  /* h-boxed row from ITER-8 */          \
      vsum.x -= oldr.x; vsum.y -= oldr.y;                                  \
      vsum.z -= oldr.z; vsum.w -= oldr.w;                                  \
    }                                                                      \
    ring[(J) & 7] = make_float4(hx, hy, hz, hw);                           \
    pxl0[(J) & 3] = al0; pxl1[(J) & 3] = al1; pxl2[(J) & 3] = al2;         \
    pxr0[(J) & 3] = rca; pxr1[(J) & 3] = rcb; pxr2[(J) & 3] = rcc;         \
    /* rotate packets: B -> A, C -> B (renamed, not moved, under unroll) */\
    al0 = bl0; al1 = bl1; al2 = bl2;                                       \
    aw0 = bw0; aw1 = bw1;                                                  \
    ag00 = bg00; ag01 = bg01; ag10 = bg10; ag11 = bg11;                    \
    ag20 = bg20; ag21 = bg21;                                              \
    dB = dC; bl0 = cl0; bl1 = cl1; bl2 = cl2;                              \
  }

__global__ __launch_bounds__(256)
void fused_loss_kernel(const float* __restrict__ left,
                       const float* __restrict__ right,
                       const float* __restrict__ disp,
                       float* __restrict__ out)
{
    const int t    = threadIdx.x;
    const int lane = t & 63;
    const int u    = blockIdx.x * 4 + (t >> 6);
    const int strip = u % NSTRIP;
    const int hseg  = (u / NSTRIP) % NSEG;
    const int n     = u / (NSTRIP * NSEG);
    const int h0 = hseg * HSEG;
    const int gc  = strip * OUTC + lane - 4;
    const int gcc = min(max(gc, 0), WW - 1);
    const bool out_lane = (lane >= 4) && (lane < 4 + OUTC) && (gc < WW);
    const size_t plane = (size_t)HH * WW;
    const float* __restrict__ dispn  = disp  + (size_t)n * plane;
    const float* __restrict__ leftn  = left  + (size_t)n * CC * plane;
    const float* __restrict__ rightn = right + (size_t)n * CC * plane;
    const int r0 = h0 - 4;

    float4 ring[8];                       // h-boxed row history (depth 8)
    float pxl0[4], pxl1[4], pxl2[4];      // center-row pixel history (delay 4)
    float pxr0[4], pxr1[4], pxr2[4];

    // ---- prologue: load packets for rows r0 (A) and r0+1 (B) ----
    int rcl = min(max(r0, 0), HH - 1);
    size_t ro = (size_t)rcl * WW + gcc;
    float dA  = dispn[ro];
    float al0 = leftn[ro], al1 = leftn[plane + ro], al2 = leftn[2 * plane + ro];
    rcl = min(max(r0 + 1, 0), HH - 1);
    ro  = (size_t)rcl * WW + gcc;
    float dB  = dispn[ro];
    float bl0 = leftn[ro], bl1 = leftn[plane + ro], bl2 = leftn[2 * plane + ro];

    float aw0, aw1, ag00, ag01, ag10, ag11, ag20, ag21;
    {
        float ix  = (float)gc - dA;
        float x0f = floorf(ix), wx = ix - x0f;
        int x0i = (int)x0f, x1i = x0i + 1;
        float v0 = (x0i >= 0 && x0i < WW) ? 1.f : 0.f;
        float v1 = (x1i >= 0 && x1i < WW) ? 1.f : 0.f;
        int i0 = min(max(x0i, 0), WW - 1), i1 = min(max(x1i, 0), WW - 1);
        aw0 = v0 * (1.f - wx); aw1 = v1 * wx;
        size_t rb = (size_t)min(max(r0, 0), HH - 1) * WW;
        ag00 = rightn[rb + i0];             ag01 = rightn[rb + i1];
        ag10 = rightn[plane + rb + i0];     ag11 = rightn[plane + rb + i1];
        ag20 = rightn[2 * plane + rb + i0]; ag21 = rightn[2 * plane + rb + i1];
    }

    float4 vsum = make_float4(0.f, 0.f, 0.f, 0.f);
    float acc = 0.f;

    // ---- staging: iters 0..7 (fills ring + pixel history; no output) ----
#pragma unroll
    for (int j = 0; j < 8; ++j) ITER_BODY(j, j, false)

    // ---- steady state: iters 8..31, one output row each ----
    for (int big = 1; big < 4; ++big) {
        const int base = big * 8;
#pragma unroll
        for (int j = 0; j < 8; ++j) ITER_BODY(j, base + j, true)
    }

    // ---- reduction: wave shuffle -> LDS (4 slots) -> atomic ----
#pragma unroll
    for (int off = 32; off > 0; off >>= 1)
        acc += __shfl_down(acc, off, 64);
    __shared__ float red[4];
    if (lane == 0) red[t >> 6] = acc;
    __syncthreads();
    if (t == 0) {
        float sred = red[0] + red[1] + red[2] + red[3];
        const float inv_count = 1.f / ((float)NB * CC * HH * WW);
        atomicAdd(out, sred * inv_count);
    }
}

extern "C" void kernel_launch(void* const* d_in, const int* in_sizes, int n_in,
                              void* d_out, int out_size, void* d_ws, size_t ws_size,
                              hipStream_t stream) {
    const float* left  = (const float*)d_in[0];
    const float* right = (const float*)d_in[1];
    const float* disp  = (const float*)d_in[2];
    float* out = (float*)d_out;

    hipMemsetAsync(out, 0, sizeof(float) * out_size, stream);

    hipLaunchKernelGGL(fused_loss_kernel, dim3(NBLK), dim3(256), 0, stream,
                       left, right, disp, out);
}